// Round 2
// baseline (462.896 us; speedup 1.0000x reference)
//
#include <hip/hip_runtime.h>
#include <hip/hip_bf16.h>

// ConceptBottleneck fused kernel, MI355X (gfx950).
// B=8192, IN=768, C=64, H=64, E=16.  Inputs/outputs fp32; internal math bf16 MFMA.
// Kernel 1 (cvt_all): fp32 -> bf16 repack of x + all weights into d_ws.
// Kernel 2 (cb_fused): grid (B/128, C); each block = 128-row batch tile x one
// concept, full pipeline (pos bank -> neg bank -> cp net -> gate) in LDS.

#define B_   8192
#define IN_  768
#define C_   64
#define H_   64
#define E_   16
#define BM_  128

typedef __bf16 bf16x8 __attribute__((ext_vector_type(8)));
typedef float  f32x4  __attribute__((ext_vector_type(4)));

// LDS plan (44,672 B -> 3 blocks/CU):
//  ubuf (15360 B): GEMM1: xs[r*40+k] (r<128,k<32) | wt[n*40+k] at +5120 (n<64,k<32)
//                  K<=64 phases: wt2[n*72+k] (n<64,k<64)   (aliases, phase-separated)
//  hbuf (18432 B): h activations [128][72]
//  xcb  (10240 B): pos|neg embeddings [128][40] (cols 0..15 pos, 16..31 neg)
struct __align__(16) Smem {
  __bf16 ubuf[7680];
  __bf16 hbuf[BM_ * 72];
  __bf16 xcb[BM_ * 40];
  float  conc[BM_];
  __bf16 w3s[64];
};
static_assert(sizeof(Smem) <= 65536, "LDS overflow");

__device__ __forceinline__ f32x4 mfma16(bf16x8 a, bf16x8 b, f32x4 c) {
  return __builtin_amdgcn_mfma_f32_16x16x32_bf16(a, b, c, 0, 0, 0);
}

__device__ __forceinline__ bf16x8 cvt8(float4 a, float4 b) {
  bf16x8 r;
  r[0] = (__bf16)a.x; r[1] = (__bf16)a.y; r[2] = (__bf16)a.z; r[3] = (__bf16)a.w;
  r[4] = (__bf16)b.x; r[5] = (__bf16)b.y; r[6] = (__bf16)b.z; r[7] = (__bf16)b.w;
  return r;
}

// 8 contiguous elements -> bf16x8 (bf16: one b128; fp32: two b128 + cvt)
template <typename T>
__device__ __forceinline__ bf16x8 ld8(const T* p) {
  if constexpr (sizeof(T) == 2) {
    return __builtin_bit_cast(bf16x8, *(const uint4*)(const void*)p);
  } else {
    const float4* q = (const float4*)(const void*)p;
    return cvt8(q[0], q[1]);
  }
}

__device__ __forceinline__ void zero_acc(f32x4 (&acc)[2][4]) {
  const f32x4 z = {0.f, 0.f, 0.f, 0.f};
#pragma unroll
  for (int mt = 0; mt < 2; ++mt)
#pragma unroll
    for (int nt = 0; nt < 4; ++nt) acc[mt][nt] = z;
}

// Stage a [K x 64] row-major global tile, transposed, into wt2[n*72+k].
// Rotated scatter breaks the deltaRow=8 bank collision (-> ~2-way).
template <typename T>
__device__ __forceinline__ void stage_wT72(const T* __restrict__ Wg,
                                           __bf16* __restrict__ wt2, int K, int tid) {
  const int ng = tid & 7;
  for (int k = tid >> 3; k < K; k += 32) {
    bf16x8 wv = ld8(Wg + (size_t)k * 64 + ng * 8);
#pragma unroll
    for (int s = 0; s < 8; ++s) {
      int i = (s + ng) & 7;
      wt2[(ng * 8 + i) * 72 + k] = wv[i];
    }
  }
}

// Epilogue: C/D frags (col=lane&15, row=quad*4+reg) + fp32 bias, relu, -> hbuf bf16.
__device__ __forceinline__ void epi_store(__bf16* __restrict__ hb, f32x4 (&acc)[2][4],
                                          const float* __restrict__ bias,
                                          int wave, int quad, int l16) {
#pragma unroll
  for (int nt = 0; nt < 4; ++nt) {
    const int col = nt * 16 + l16;
    const float bv = bias[col];
#pragma unroll
    for (int mt = 0; mt < 2; ++mt)
#pragma unroll
      for (int r = 0; r < 4; ++r) {
        int row = wave * 32 + mt * 16 + quad * 4 + r;
        hb[row * 72 + col] = (__bf16)fmaxf(acc[mt][nt][r] + bv, 0.f);
      }
  }
}

// [128,64] @ [64,64] from hbuf (A) and wt2 (B in [n][k] layout), K=64 = 2 k-steps.
__device__ __forceinline__ void gemm64c(const __bf16* __restrict__ hb,
                                        const __bf16* __restrict__ wt2,
                                        f32x4 (&acc)[2][4], int wave, int quad, int l16) {
#pragma unroll
  for (int ks = 0; ks < 2; ++ks) {
    bf16x8 a[2], bb[4];
#pragma unroll
    for (int mt = 0; mt < 2; ++mt)
      a[mt] = *(const bf16x8*)(hb + (wave * 32 + mt * 16 + l16) * 72 + ks * 32 + quad * 8);
#pragma unroll
    for (int nt = 0; nt < 4; ++nt)
      bb[nt] = *(const bf16x8*)(wt2 + (nt * 16 + l16) * 72 + ks * 32 + quad * 8);
#pragma unroll
    for (int mt = 0; mt < 2; ++mt)
#pragma unroll
      for (int nt = 0; nt < 4; ++nt)
        acc[mt][nt] = mfma16(a[mt], bb[nt], acc[mt][nt]);
  }
}

// One bank: h1=relu(x@W1c+b1); h2=relu(h1@W2c+b2); e=h2@W3c+b3 -> xcb[:, xc_off..+16)
template <typename T>
__device__ __forceinline__ void run_bank(Smem& sm, const T* __restrict__ x,
    const T* __restrict__ W1, const float* __restrict__ b1,
    const T* __restrict__ W2, const float* __restrict__ b2,
    const T* __restrict__ W3, const float* __restrict__ b3,
    int c, int row0, int xc_off, int tid, int wave, int quad, int l16)
{
  __bf16* xs  = sm.ubuf;                 // [128][40]
  __bf16* wt  = sm.ubuf + BM_ * 40;      // [64][40]
  __bf16* wt2 = sm.ubuf;                 // [64][72] (aliases, phase-separated)
  __bf16* hb  = sm.hbuf;

  // ---------- layer 1: [128,768] @ [768,64] ----------
  f32x4 acc1[2][4]; zero_acc(acc1);
  const T* W1c = W1 + (size_t)c * (IN_ * H_);
  const int xr = tid >> 2, xg = tid & 3;   // x-stage: 2 rows x 8 cols per thread
  const int wk = tid >> 3, wng = tid & 7;  // w-stage: 8 cols per thread
  for (int kt = 0; kt < IN_ / 32; ++kt) {
    bf16x8 xv0 = ld8(x + (size_t)(row0 + xr) * IN_ + kt * 32 + xg * 8);
    bf16x8 xv1 = ld8(x + (size_t)(row0 + xr + 64) * IN_ + kt * 32 + xg * 8);
    bf16x8 wv  = ld8(W1c + (size_t)(kt * 32 + wk) * H_ + wng * 8);
    *(uint4*)&xs[xr * 40 + xg * 8]        = __builtin_bit_cast(uint4, xv0);
    *(uint4*)&xs[(xr + 64) * 40 + xg * 8] = __builtin_bit_cast(uint4, xv1);
#pragma unroll
    for (int s = 0; s < 8; ++s) {          // rotated transpose-scatter
      int i = (s + wng) & 7;
      wt[(wng * 8 + i) * 40 + wk] = wv[i];
    }
    __syncthreads();
    bf16x8 a[2], bb[4];
#pragma unroll
    for (int mt = 0; mt < 2; ++mt)
      a[mt] = *(const bf16x8*)&xs[(wave * 32 + mt * 16 + l16) * 40 + quad * 8];
#pragma unroll
    for (int nt = 0; nt < 4; ++nt)
      bb[nt] = *(const bf16x8*)&wt[(nt * 16 + l16) * 40 + quad * 8];
#pragma unroll
    for (int mt = 0; mt < 2; ++mt)
#pragma unroll
      for (int nt = 0; nt < 4; ++nt)
        acc1[mt][nt] = mfma16(a[mt], bb[nt], acc1[mt][nt]);
    __syncthreads();
  }
  epi_store(hb, acc1, b1 + c * H_, wave, quad, l16);

  // ---------- layer 2: [128,64] @ [64,64] ----------
  stage_wT72(W2 + (size_t)c * (H_ * H_), wt2, 64, tid);
  __syncthreads();
  f32x4 acc2[2][4]; zero_acc(acc2);
  gemm64c(hb, wt2, acc2, wave, quad, l16);
  __syncthreads();
  epi_store(hb, acc2, b2 + c * H_, wave, quad, l16);

  // ---------- layer 3: [128,64] @ [64,16] ----------
  {
    const T* W3c = W3 + (size_t)c * (H_ * E_);
    if (tid < 128) {
      int h = tid >> 1, eg = tid & 1;
      bf16x8 wv = ld8(W3c + (size_t)h * E_ + eg * 8);
#pragma unroll
      for (int i = 0; i < 8; ++i) wt2[(eg * 8 + i) * 72 + h] = wv[i];
    }
  }
  __syncthreads();
  f32x4 acc3[2];
  {
    const f32x4 z = {0.f, 0.f, 0.f, 0.f};
    acc3[0] = z; acc3[1] = z;
  }
#pragma unroll
  for (int ks = 0; ks < 2; ++ks) {
    bf16x8 bb = *(const bf16x8*)&wt2[l16 * 72 + ks * 32 + quad * 8];
#pragma unroll
    for (int mt = 0; mt < 2; ++mt) {
      bf16x8 a = *(const bf16x8*)&hb[(wave * 32 + mt * 16 + l16) * 72 + ks * 32 + quad * 8];
      acc3[mt] = mfma16(a, bb, acc3[mt]);
    }
  }
  __syncthreads();
  {
    float bv = b3[c * E_ + l16];
#pragma unroll
    for (int mt = 0; mt < 2; ++mt)
#pragma unroll
      for (int r = 0; r < 4; ++r) {
        int row = wave * 32 + mt * 16 + quad * 4 + r;
        sm.xcb[row * 40 + xc_off + l16] = (__bf16)(acc3[mt][r] + bv);
      }
  }
  __syncthreads();
}

template <typename T>
__global__ __launch_bounds__(256) void cb_fused(
    const T* __restrict__ x,
    const T* __restrict__ pW1, const float* __restrict__ pb1,
    const T* __restrict__ pW2, const float* __restrict__ pb2,
    const T* __restrict__ pW3, const float* __restrict__ pb3,
    const T* __restrict__ nW1, const float* __restrict__ nb1,
    const T* __restrict__ nW2, const float* __restrict__ nb2,
    const T* __restrict__ nW3, const float* __restrict__ nb3,
    const T* __restrict__ cW1, const float* __restrict__ cb1,
    const T* __restrict__ cW2, const float* __restrict__ cb2,
    const T* __restrict__ cW3, const float* __restrict__ cb3,
    float* __restrict__ out_emb, float* __restrict__ out_con)
{
  __shared__ Smem sm;
  const int tid  = threadIdx.x;
  const int wave = tid >> 6, lane = tid & 63;
  const int quad = lane >> 4, l16 = lane & 15;
  const int row0 = blockIdx.x * BM_;
  const int c    = blockIdx.y;
  __bf16* wt2 = sm.ubuf;
  __bf16* hb  = sm.hbuf;

  run_bank(sm, x, pW1, pb1, pW2, pb2, pW3, pb3, c, row0, 0,  tid, wave, quad, l16);
  run_bank(sm, x, nW1, nb1, nW2, nb2, nW3, nb3, c, row0, 16, tid, wave, quad, l16);

  // ---- cp layer 1: [128,32] @ [32,64], A = xcb ----
  stage_wT72(cW1 + (size_t)c * (2 * E_ * H_), wt2, 2 * E_, tid);
  __syncthreads();
  f32x4 acc1[2][4]; zero_acc(acc1);
  {
    bf16x8 a[2], bb[4];
#pragma unroll
    for (int mt = 0; mt < 2; ++mt)
      a[mt] = *(const bf16x8*)&sm.xcb[(wave * 32 + mt * 16 + l16) * 40 + quad * 8];
#pragma unroll
    for (int nt = 0; nt < 4; ++nt)
      bb[nt] = *(const bf16x8*)&wt2[(nt * 16 + l16) * 72 + quad * 8];
#pragma unroll
    for (int mt = 0; mt < 2; ++mt)
#pragma unroll
      for (int nt = 0; nt < 4; ++nt)
        acc1[mt][nt] = mfma16(a[mt], bb[nt], acc1[mt][nt]);
  }
  __syncthreads();
  epi_store(hb, acc1, cb1 + c * H_, wave, quad, l16);

  // ---- cp layer 2 ----
  stage_wT72(cW2 + (size_t)c * (H_ * H_), wt2, 64, tid);
  __syncthreads();
  f32x4 acc2[2][4]; zero_acc(acc2);
  gemm64c(hb, wt2, acc2, wave, quad, l16);
  __syncthreads();
  epi_store(hb, acc2, cb2 + c * H_, wave, quad, l16);

  // ---- cp layer 3 (N=1, VALU dot) ----
  if (tid < 64) sm.w3s[tid] = (__bf16)(float)cW3[(size_t)c * H_ + tid];
  __syncthreads();
  if (tid < 128) {
    float s = cb3[c];
#pragma unroll
    for (int kc = 0; kc < 8; ++kc) {
      bf16x8 hv = *(const bf16x8*)&hb[tid * 72 + kc * 8];
      bf16x8 wv = *(const bf16x8*)&sm.w3s[kc * 8];
#pragma unroll
      for (int i = 0; i < 8; ++i) s += (float)hv[i] * (float)wv[i];
    }
    sm.conc[tid] = s;
  }
  __syncthreads();

  // ---- gate + outputs (fp32) ----
  for (int ii = tid; ii < BM_ * E_; ii += 256) {
    int row = ii >> 4, e = ii & 15;
    float cv = sm.conc[row];
    float w  = fminf(fmaxf(cv * 0.5f + 0.5f, 0.f), 1.f);
    float pv = (float)sm.xcb[row * 40 + e];
    float nv = (float)sm.xcb[row * 40 + 16 + e];
    out_emb[(size_t)(row0 + row) * (E_ * C_) + e * C_ + c] = pv * w + nv * (1.f - w);
  }
  if (tid < 128) out_con[(size_t)(row0 + tid) * C_ + c] = sm.conc[tid];
}

// ---------------- fp32 -> bf16 repack of x + weights into d_ws ----------------
#define NSEG 10
struct CvtArgs {
  const float* src[NSEG];
  __bf16*      dst[NSEG];
  int          cnt8[NSEG];   // element count / 8 per segment
  int          total8;
};

__global__ __launch_bounds__(256) void cvt_all(CvtArgs a) {
  for (int idx = blockIdx.x * 256 + threadIdx.x; idx < a.total8; idx += gridDim.x * 256) {
    int off = idx, seg = 0;
    while (seg < NSEG - 1 && off >= a.cnt8[seg]) { off -= a.cnt8[seg]; ++seg; }
    const float4* s = (const float4*)(a.src[seg]) + (size_t)off * 2;
    float4 v0 = s[0], v1 = s[1];
    bf16x8 r = cvt8(v0, v1);
    *(uint4*)(a.dst[seg] + (size_t)off * 8) = __builtin_bit_cast(uint4, r);
  }
}

extern "C" void kernel_launch(void* const* d_in, const int* in_sizes, int n_in,
                              void* d_out, int out_size, void* d_ws, size_t ws_size,
                              hipStream_t stream) {
  const float* xf   = (const float*)d_in[0];
  const float* pW1f = (const float*)d_in[1];
  const float* pb1f = (const float*)d_in[2];
  const float* pW2f = (const float*)d_in[3];
  const float* pb2f = (const float*)d_in[4];
  const float* pW3f = (const float*)d_in[5];
  const float* pb3f = (const float*)d_in[6];
  const float* nW1f = (const float*)d_in[7];
  const float* nb1f = (const float*)d_in[8];
  const float* nW2f = (const float*)d_in[9];
  const float* nb2f = (const float*)d_in[10];
  const float* nW3f = (const float*)d_in[11];
  const float* nb3f = (const float*)d_in[12];
  const float* cW1f = (const float*)d_in[13];
  const float* cb1f = (const float*)d_in[14];
  const float* cW2f = (const float*)d_in[15];
  const float* cb2f = (const float*)d_in[16];
  const float* cW3f = (const float*)d_in[17];
  const float* cb3f = (const float*)d_in[18];

  float* out_emb = (float*)d_out;
  float* out_con = out_emb + (size_t)B_ * E_ * C_;

  // segment element counts (all multiples of 8)
  const int cx   = B_ * IN_;            // 6291456
  const int cW1c = C_ * IN_ * H_;       // 3145728
  const int cW2c = C_ * H_ * H_;        // 262144
  const int cW3c = C_ * H_ * E_;        // 65536
  const int ccW1 = C_ * 2 * E_ * H_;    // 131072
  const int ccW3 = C_ * H_;             // 4096
  const size_t total_el = (size_t)cx + 2 * cW1c + 3 * cW2c + 2 * cW3c + ccW1 + ccW3;
  const size_t need = total_el * 2;

  dim3 grid(B_ / BM_, C_);

  if (ws_size >= need) {
    __bf16* w = (__bf16*)d_ws;
    __bf16 *xw = w, *pw1, *nw1, *pw2, *pw3, *nw2, *nw3, *cw1, *cw2, *cw3;
    size_t o = cx;
    pw1 = w + o; o += cW1c;
    nw1 = w + o; o += cW1c;
    pw2 = w + o; o += cW2c;
    pw3 = w + o; o += cW3c;
    nw2 = w + o; o += cW2c;
    nw3 = w + o; o += cW3c;
    cw1 = w + o; o += ccW1;
    cw2 = w + o; o += cW2c;
    cw3 = w + o; o += ccW3;

    CvtArgs a;
    const float* srcs[NSEG] = {xf, pW1f, nW1f, pW2f, pW3f, nW2f, nW3f, cW1f, cW2f, cW3f};
    __bf16*      dsts[NSEG] = {xw, pw1,  nw1,  pw2,  pw3,  nw2,  nw3,  cw1,  cw2,  cw3};
    const int    cnts[NSEG] = {cx, cW1c, cW1c, cW2c, cW3c, cW2c, cW3c, ccW1, cW2c, ccW3};
    int total8 = 0;
    for (int i = 0; i < NSEG; ++i) {
      a.src[i] = srcs[i]; a.dst[i] = dsts[i]; a.cnt8[i] = cnts[i] / 8;
      total8 += cnts[i] / 8;
    }
    a.total8 = total8;
    int cvt_blocks = (total8 + 255) / 256;
    cvt_all<<<cvt_blocks, 256, 0, stream>>>(a);

    cb_fused<__bf16><<<grid, 256, 0, stream>>>(xw,
        pw1, pb1f, pw2, pb2f, pw3, pb3f,
        nw1, nb1f, nw2, nb2f, nw3, nb3f,
        cw1, cb1f, cw2, cb2f, cw3, cb3f,
        out_emb, out_con);
  } else {
    // fallback: stream fp32 directly with inline conversion
    cb_fused<float><<<grid, 256, 0, stream>>>(xf,
        pW1f, pb1f, pW2f, pb2f, pW3f, pb3f,
        nW1f, nb1f, nW2f, nb2f, nW3f, nb3f,
        cW1f, cb1f, cW2f, cb2f, cW3f, cb3f,
        out_emb, out_con);
  }
}

// Round 3
// 364.008 us; speedup vs baseline: 1.2717x; 1.2717x over previous
//
#include <hip/hip_runtime.h>
#include <hip/hip_bf16.h>

// ConceptBottleneck fused kernel, MI355X (gfx950).
// B=8192, IN=768, C=64, H=64, E=16.  Inputs/outputs fp32; internal math bf16 MFMA.
// prep: fp32->bf16 convert x, and convert+TRANSPOSE all weights into d_ws so the
//       hot kernel stages W tiles with contiguous ds_write_b128 (no scalar scatter).
// cb_fused_t: grid (B/128, C); block = 128-row batch tile x one concept.

#define B_   8192
#define IN_  768
#define C_   64
#define H_   64
#define E_   16
#define BM_  128

typedef __bf16 bf16x8 __attribute__((ext_vector_type(8)));
typedef float  f32x4  __attribute__((ext_vector_type(4)));

__device__ __forceinline__ f32x4 mfma16(bf16x8 a, bf16x8 b, f32x4 c) {
  return __builtin_amdgcn_mfma_f32_16x16x32_bf16(a, b, c, 0, 0, 0);
}

__device__ __forceinline__ bf16x8 cvt8(float4 a, float4 b) {
  bf16x8 r;
  r[0] = (__bf16)a.x; r[1] = (__bf16)a.y; r[2] = (__bf16)a.z; r[3] = (__bf16)a.w;
  r[4] = (__bf16)b.x; r[5] = (__bf16)b.y; r[6] = (__bf16)b.z; r[7] = (__bf16)b.w;
  return r;
}

template <typename T>
__device__ __forceinline__ bf16x8 ld8(const T* p) {
  if constexpr (sizeof(T) == 2) {
    return __builtin_bit_cast(bf16x8, *(const uint4*)(const void*)p);
  } else {
    const float4* q = (const float4*)(const void*)p;
    return cvt8(q[0], q[1]);
  }
}

__device__ __forceinline__ void zero_acc(f32x4 (&acc)[2][4]) {
  const f32x4 z = {0.f, 0.f, 0.f, 0.f};
#pragma unroll
  for (int mt = 0; mt < 2; ++mt)
#pragma unroll
    for (int nt = 0; nt < 4; ++nt) acc[mt][nt] = z;
}

// ============================ FAST PATH =====================================
// LDS (38400 B -> 4 blocks/CU):
//  xs [128][72] : x tile during L1; aliased as hb (activations) afterwards
//  wt [64][72]  : weight tile in [n][k] layout (phase-multiplexed)
//  xcb[128][40] : pos|neg embeddings (cols 0..15 pos, 16..31 neg)
struct __align__(16) SmemT {
  __bf16 xs[BM_ * 72];
  __bf16 wt[64 * 72];
  __bf16 xcb[BM_ * 40];
  float  conc[BM_];
};
static_assert(sizeof(SmemT) <= 40960, "LDS overflow");

// Epilogue: C/D frags (col=lane&15, row=quad*4+reg) + fp32 bias, relu -> hb (stride 72)
__device__ __forceinline__ void epi72(__bf16* __restrict__ hb, f32x4 (&acc)[2][4],
                                      const float* __restrict__ bias,
                                      int wave, int quad, int l16) {
#pragma unroll
  for (int nt = 0; nt < 4; ++nt) {
    const int col = nt * 16 + l16;
    const float bv = bias[col];
#pragma unroll
    for (int mt = 0; mt < 2; ++mt)
#pragma unroll
      for (int r = 0; r < 4; ++r) {
        int row = wave * 32 + mt * 16 + quad * 4 + r;
        hb[row * 72 + col] = (__bf16)fmaxf(acc[mt][nt][r] + bv, 0.f);
      }
  }
}

// [128,64] @ [64,64]: A=hb (stride 72), B=wt [n][k] (stride 72), K=64.
__device__ __forceinline__ void gemm64(const __bf16* __restrict__ hb,
                                       const __bf16* __restrict__ wt,
                                       f32x4 (&acc)[2][4], int wave, int quad, int l16) {
#pragma unroll
  for (int ks = 0; ks < 2; ++ks) {
    bf16x8 a[2], bb[4];
#pragma unroll
    for (int mt = 0; mt < 2; ++mt)
      a[mt] = *(const bf16x8*)(hb + (wave * 32 + mt * 16 + l16) * 72 + ks * 32 + quad * 8);
#pragma unroll
    for (int nt = 0; nt < 4; ++nt)
      bb[nt] = *(const bf16x8*)(wt + (nt * 16 + l16) * 72 + ks * 32 + quad * 8);
#pragma unroll
    for (int mt = 0; mt < 2; ++mt)
#pragma unroll
      for (int nt = 0; nt < 4; ++nt)
        acc[mt][nt] = mfma16(a[mt], bb[nt], acc[mt][nt]);
  }
}

// Stage [64][64] bf16 tile (row-major, contiguous) into wt (stride 72). 2 b128/thread.
__device__ __forceinline__ void stage_w64(const __bf16* __restrict__ Wt,
                                          __bf16* __restrict__ wt, int tid) {
#pragma unroll
  for (int it = 0; it < 2; ++it) {
    int q = tid + it * 256;            // chunk id over 512 x 16B
    int n = q >> 3, i = q & 7;
    *(uint4*)&wt[n * 72 + i * 8] = *(const uint4*)(Wt + n * 64 + i * 8);
  }
}

// One bank: h1=relu(x@W1+b1); h2=relu(h1@W2+b2); e=h2@W3+b3 -> xcb[:, xc_off..+16)
// W1t: [64][768], W2t: [64][64], W3t: [16][64]  (transposed, bf16)
__device__ __forceinline__ void run_bank_t(SmemT& sm, const __bf16* __restrict__ x,
    const __bf16* __restrict__ W1t, const float* __restrict__ b1,
    const __bf16* __restrict__ W2t, const float* __restrict__ b2,
    const __bf16* __restrict__ W3t, const float* __restrict__ b3,
    int row0, int xc_off, int tid, int wave, int quad, int l16)
{
  __bf16* xs = sm.xs;
  __bf16* wt = sm.wt;
  __bf16* hb = sm.xs;   // alias: safe, xs dead after L1 loop's final barrier

  // ---------- layer 1: [128,768] @ [768,64], BK=64 ----------
  f32x4 acc1[2][4]; zero_acc(acc1);
  const int xrow = tid >> 3, xi = tid & 7;   // x chunks: 1024 x 16B, 4 iters
  const int wn = tid >> 3, wi = tid & 7;     // w chunks: 512 x 16B, 2 iters
  for (int kt = 0; kt < IN_ / 64; ++kt) {
    uint4 xv[4], wv[2];
#pragma unroll
    for (int it = 0; it < 4; ++it) {
      int row = xrow + it * 32;
      xv[it] = *(const uint4*)(x + (size_t)(row0 + row) * IN_ + kt * 64 + xi * 8);
    }
#pragma unroll
    for (int it = 0; it < 2; ++it) {
      int n = wn + it * 32;
      wv[it] = *(const uint4*)(W1t + (size_t)n * IN_ + kt * 64 + wi * 8);
    }
#pragma unroll
    for (int it = 0; it < 4; ++it)
      *(uint4*)&xs[(xrow + it * 32) * 72 + xi * 8] = xv[it];
#pragma unroll
    for (int it = 0; it < 2; ++it)
      *(uint4*)&wt[(wn + it * 32) * 72 + wi * 8] = wv[it];
    __syncthreads();
#pragma unroll
    for (int ks = 0; ks < 2; ++ks) {
      bf16x8 a[2], bb[4];
#pragma unroll
      for (int mt = 0; mt < 2; ++mt)
        a[mt] = *(const bf16x8*)&xs[(wave * 32 + mt * 16 + l16) * 72 + ks * 32 + quad * 8];
#pragma unroll
      for (int nt = 0; nt < 4; ++nt)
        bb[nt] = *(const bf16x8*)&wt[(nt * 16 + l16) * 72 + ks * 32 + quad * 8];
#pragma unroll
      for (int mt = 0; mt < 2; ++mt)
#pragma unroll
        for (int nt = 0; nt < 4; ++nt)
          acc1[mt][nt] = mfma16(a[mt], bb[nt], acc1[mt][nt]);
    }
    __syncthreads();
  }
  epi72(hb, acc1, b1, wave, quad, l16);   // writes xs region (reads drained)
  stage_w64(W2t, wt, tid);                // disjoint region, same phase
  __syncthreads();

  // ---------- layer 2: [128,64] @ [64,64] ----------
  f32x4 acc2[2][4]; zero_acc(acc2);
  gemm64(hb, wt, acc2, wave, quad, l16);
  __syncthreads();
  epi72(hb, acc2, b2, wave, quad, l16);
  if (tid < 128)                           // stage W3t [16][64]
    *(uint4*)&wt[(tid >> 3) * 72 + (tid & 7) * 8] =
        *(const uint4*)(W3t + (tid >> 3) * 64 + (tid & 7) * 8);
  __syncthreads();

  // ---------- layer 3: [128,64] @ [64,16] ----------
  f32x4 acc3[2];
  { const f32x4 z = {0.f, 0.f, 0.f, 0.f}; acc3[0] = z; acc3[1] = z; }
#pragma unroll
  for (int ks = 0; ks < 2; ++ks) {
    bf16x8 bb = *(const bf16x8*)&wt[l16 * 72 + ks * 32 + quad * 8];
#pragma unroll
    for (int mt = 0; mt < 2; ++mt) {
      bf16x8 a = *(const bf16x8*)&hb[(wave * 32 + mt * 16 + l16) * 72 + ks * 32 + quad * 8];
      acc3[mt] = mfma16(a, bb, acc3[mt]);
    }
  }
  {
    float bv = b3[l16];
#pragma unroll
    for (int mt = 0; mt < 2; ++mt)
#pragma unroll
      for (int r = 0; r < 4; ++r) {
        int row = wave * 32 + mt * 16 + quad * 4 + r;
        sm.xcb[row * 40 + xc_off + l16] = (__bf16)(acc3[mt][r] + bv);
      }
  }
  __syncthreads();
}

__global__ __launch_bounds__(256, 4) void cb_fused_t(
    const __bf16* __restrict__ x,
    const __bf16* __restrict__ pW1t, const float* __restrict__ pb1,
    const __bf16* __restrict__ pW2t, const float* __restrict__ pb2,
    const __bf16* __restrict__ pW3t, const float* __restrict__ pb3,
    const __bf16* __restrict__ nW1t, const float* __restrict__ nb1,
    const __bf16* __restrict__ nW2t, const float* __restrict__ nb2,
    const __bf16* __restrict__ nW3t, const float* __restrict__ nb3,
    const __bf16* __restrict__ cW1t, const float* __restrict__ cb1,
    const __bf16* __restrict__ cW2t, const float* __restrict__ cb2,
    const __bf16* __restrict__ cw3,  const float* __restrict__ cb3,
    float* __restrict__ out_emb, float* __restrict__ out_con)
{
  __shared__ SmemT sm;
  const int tid  = threadIdx.x;
  const int wave = tid >> 6, lane = tid & 63;
  const int quad = lane >> 4, l16 = lane & 15;
  const int row0 = blockIdx.x * BM_;
  const int c    = blockIdx.y;
  __bf16* hb = sm.xs;
  __bf16* wt = sm.wt;

  run_bank_t(sm, x, pW1t + (size_t)c * 64 * IN_, pb1 + c * 64,
             pW2t + (size_t)c * 64 * 64, pb2 + c * 64,
             pW3t + (size_t)c * 16 * 64, pb3 + c * 16,
             row0, 0, tid, wave, quad, l16);
  run_bank_t(sm, x, nW1t + (size_t)c * 64 * IN_, nb1 + c * 64,
             nW2t + (size_t)c * 64 * 64, nb2 + c * 64,
             nW3t + (size_t)c * 16 * 64, nb3 + c * 16,
             row0, 16, tid, wave, quad, l16);

  // ---- cp layer 1: [128,32] @ [32,64]; A = xcb (stride 40), B = cW1t [64][32] ----
  {
    int n = tid >> 2, i = tid & 3;
    *(uint4*)&wt[n * 72 + i * 8] = *(const uint4*)(cW1t + ((size_t)c * 64 + n) * 32 + i * 8);
  }
  __syncthreads();
  f32x4 acc1[2][4]; zero_acc(acc1);
  {
    bf16x8 a[2], bb[4];
#pragma unroll
    for (int mt = 0; mt < 2; ++mt)
      a[mt] = *(const bf16x8*)&sm.xcb[(wave * 32 + mt * 16 + l16) * 40 + quad * 8];
#pragma unroll
    for (int nt = 0; nt < 4; ++nt)
      bb[nt] = *(const bf16x8*)&wt[(nt * 16 + l16) * 72 + quad * 8];
#pragma unroll
    for (int mt = 0; mt < 2; ++mt)
#pragma unroll
      for (int nt = 0; nt < 4; ++nt)
        acc1[mt][nt] = mfma16(a[mt], bb[nt], acc1[mt][nt]);
  }
  __syncthreads();
  epi72(hb, acc1, cb1 + c * 64, wave, quad, l16);
  stage_w64(cW2t + (size_t)c * 64 * 64, wt, tid);
  __syncthreads();

  // ---- cp layer 2 ----
  f32x4 acc2[2][4]; zero_acc(acc2);
  gemm64(hb, wt, acc2, wave, quad, l16);
  __syncthreads();
  epi72(hb, acc2, cb2 + c * 64, wave, quad, l16);
  if (tid < 8) *(uint4*)&wt[tid * 8] = *(const uint4*)(cw3 + (size_t)c * 64 + tid * 8);
  __syncthreads();

  // ---- cp layer 3 (N=1 via MFMA, B = cw3 as row n=0) ----
  f32x4 acc3[2];
  { const f32x4 z = {0.f, 0.f, 0.f, 0.f}; acc3[0] = z; acc3[1] = z; }
#pragma unroll
  for (int ks = 0; ks < 2; ++ks) {
    bf16x8 bb = {};
    if (l16 == 0) bb = *(const bf16x8*)&wt[ks * 32 + quad * 8];
#pragma unroll
    for (int mt = 0; mt < 2; ++mt) {
      bf16x8 a = *(const bf16x8*)&hb[(wave * 32 + mt * 16 + l16) * 72 + ks * 32 + quad * 8];
      acc3[mt] = mfma16(a, bb, acc3[mt]);
    }
  }
  if (l16 == 0) {
    float bv = cb3[c];
#pragma unroll
    for (int mt = 0; mt < 2; ++mt)
#pragma unroll
      for (int r = 0; r < 4; ++r)
        sm.conc[wave * 32 + mt * 16 + quad * 4 + r] = acc3[mt][r] + bv;
  }
  __syncthreads();

  // ---- gate + outputs (fp32) ----
  for (int ii = tid; ii < BM_ * E_; ii += 256) {
    int row = ii >> 4, e = ii & 15;
    float cv = sm.conc[row];
    float w  = fminf(fmaxf(cv * 0.5f + 0.5f, 0.f), 1.f);
    float pv = (float)sm.xcb[row * 40 + e];
    float nv = (float)sm.xcb[row * 40 + 16 + e];
    out_emb[(size_t)(row0 + row) * (E_ * C_) + e * C_ + c] = pv * w + nv * (1.f - w);
  }
  if (tid < 128) out_con[(size_t)(row0 + tid) * C_ + c] = sm.conc[tid];
}

// ------------------- prep: convert (+transpose) into d_ws ---------------------
// Segments: N==1 -> plain fp32->bf16 copy (vectorized).
//           N>1  -> dst[(c*N+n)*K + k] = src[c*K*N + k*N + n]  (coalesced writes)
#define PSEG 10
struct PrepArgs {
  const float* src[PSEG];
  __bf16*      dst[PSEG];
  int bstart[PSEG + 1];
  int kdiv8[PSEG];   // K/8
  int N[PSEG];       // src inner stride (1 = plain copy)
};

__global__ __launch_bounds__(256) void prep(PrepArgs a) {
  int b = blockIdx.x;
  int seg = 0;
  while (seg < PSEG - 1 && b >= a.bstart[seg + 1]) ++seg;
  int idx = (b - a.bstart[seg]) * 256 + threadIdx.x;
  int kc = a.kdiv8[seg];
  int N  = a.N[seg];
  if (N == 1) {
    const float4* s = (const float4*)a.src[seg] + (size_t)idx * 2;
    float4 v0 = s[0], v1 = s[1];
    *(uint4*)(a.dst[seg] + (size_t)idx * 8) = __builtin_bit_cast(uint4, cvt8(v0, v1));
  } else {
    int rn = idx / kc;                   // c*N + n
    int k0 = (idx - rn * kc) * 8;
    int cc = rn / N;
    int n  = rn - cc * N;
    const float* s = a.src[seg] + ((size_t)cc * kc * 8 + k0) * N + n;
    bf16x8 r;
#pragma unroll
    for (int j = 0; j < 8; ++j) r[j] = (__bf16)s[(size_t)j * N];
    *(uint4*)(a.dst[seg] + (size_t)rn * kc * 8 + k0) = __builtin_bit_cast(uint4, r);
  }
}

// ====================== FALLBACK (fp32 direct, in-kernel transpose) ==========
struct __align__(16) Smem {
  __bf16 ubuf[7680];
  __bf16 hbuf[BM_ * 72];
  __bf16 xcb[BM_ * 40];
  float  conc[BM_];
  __bf16 w3s[64];
};

template <typename T>
__device__ __forceinline__ void stage_wT72(const T* __restrict__ Wg,
                                           __bf16* __restrict__ wt2, int K, int tid) {
  const int ng = tid & 7;
  for (int k = tid >> 3; k < K; k += 32) {
    bf16x8 wv = ld8(Wg + (size_t)k * 64 + ng * 8);
#pragma unroll
    for (int s = 0; s < 8; ++s) {
      int i = (s + ng) & 7;
      wt2[(ng * 8 + i) * 72 + k] = wv[i];
    }
  }
}

template <typename T>
__device__ __forceinline__ void run_bank(Smem& sm, const T* __restrict__ x,
    const T* __restrict__ W1, const float* __restrict__ b1,
    const T* __restrict__ W2, const float* __restrict__ b2,
    const T* __restrict__ W3, const float* __restrict__ b3,
    int c, int row0, int xc_off, int tid, int wave, int quad, int l16)
{
  __bf16* xs  = sm.ubuf;
  __bf16* wt  = sm.ubuf + BM_ * 40;
  __bf16* wt2 = sm.ubuf;
  __bf16* hb  = sm.hbuf;

  f32x4 acc1[2][4]; zero_acc(acc1);
  const T* W1c = W1 + (size_t)c * (IN_ * H_);
  const int xr = tid >> 2, xg = tid & 3;
  const int wk = tid >> 3, wng = tid & 7;
  for (int kt = 0; kt < IN_ / 32; ++kt) {
    bf16x8 xv0 = ld8(x + (size_t)(row0 + xr) * IN_ + kt * 32 + xg * 8);
    bf16x8 xv1 = ld8(x + (size_t)(row0 + xr + 64) * IN_ + kt * 32 + xg * 8);
    bf16x8 wv  = ld8(W1c + (size_t)(kt * 32 + wk) * H_ + wng * 8);
    *(uint4*)&xs[xr * 40 + xg * 8]        = __builtin_bit_cast(uint4, xv0);
    *(uint4*)&xs[(xr + 64) * 40 + xg * 8] = __builtin_bit_cast(uint4, xv1);
#pragma unroll
    for (int s = 0; s < 8; ++s) {
      int i = (s + wng) & 7;
      wt[(wng * 8 + i) * 40 + wk] = wv[i];
    }
    __syncthreads();
    bf16x8 a[2], bb[4];
#pragma unroll
    for (int mt = 0; mt < 2; ++mt)
      a[mt] = *(const bf16x8*)&xs[(wave * 32 + mt * 16 + l16) * 40 + quad * 8];
#pragma unroll
    for (int nt = 0; nt < 4; ++nt)
      bb[nt] = *(const bf16x8*)&wt[(nt * 16 + l16) * 40 + quad * 8];
#pragma unroll
    for (int mt = 0; mt < 2; ++mt)
#pragma unroll
      for (int nt = 0; nt < 4; ++nt)
        acc1[mt][nt] = mfma16(a[mt], bb[nt], acc1[mt][nt]);
    __syncthreads();
  }
  {
    const float* bias = b1 + c * H_;
#pragma unroll
    for (int nt = 0; nt < 4; ++nt) {
      const int col = nt * 16 + l16;
      const float bv = bias[col];
#pragma unroll
      for (int mt = 0; mt < 2; ++mt)
#pragma unroll
        for (int r = 0; r < 4; ++r) {
          int row = wave * 32 + mt * 16 + quad * 4 + r;
          hb[row * 72 + col] = (__bf16)fmaxf(acc1[mt][nt][r] + bv, 0.f);
        }
    }
  }

  stage_wT72(W2 + (size_t)c * (H_ * H_), wt2, 64, tid);
  __syncthreads();
  f32x4 acc2[2][4]; zero_acc(acc2);
  gemm64(hb, wt2, acc2, wave, quad, l16);
  __syncthreads();
  {
    const float* bias = b2 + c * H_;
#pragma unroll
    for (int nt = 0; nt < 4; ++nt) {
      const int col = nt * 16 + l16;
      const float bv = bias[col];
#pragma unroll
      for (int mt = 0; mt < 2; ++mt)
#pragma unroll
        for (int r = 0; r < 4; ++r) {
          int row = wave * 32 + mt * 16 + quad * 4 + r;
          hb[row * 72 + col] = (__bf16)fmaxf(acc2[mt][nt][r] + bv, 0.f);
        }
    }
  }

  {
    const T* W3c = W3 + (size_t)c * (H_ * E_);
    if (tid < 128) {
      int h = tid >> 1, eg = tid & 1;
      bf16x8 wv = ld8(W3c + (size_t)h * E_ + eg * 8);
#pragma unroll
      for (int i = 0; i < 8; ++i) wt2[(eg * 8 + i) * 72 + h] = wv[i];
    }
  }
  __syncthreads();
  f32x4 acc3[2];
  { const f32x4 z = {0.f, 0.f, 0.f, 0.f}; acc3[0] = z; acc3[1] = z; }
#pragma unroll
  for (int ks = 0; ks < 2; ++ks) {
    bf16x8 bb = *(const bf16x8*)&wt2[l16 * 72 + ks * 32 + quad * 8];
#pragma unroll
    for (int mt = 0; mt < 2; ++mt) {
      bf16x8 a = *(const bf16x8*)&hb[(wave * 32 + mt * 16 + l16) * 72 + ks * 32 + quad * 8];
      acc3[mt] = mfma16(a, bb, acc3[mt]);
    }
  }
  __syncthreads();
  {
    float bv = b3[c * E_ + l16];
#pragma unroll
    for (int mt = 0; mt < 2; ++mt)
#pragma unroll
      for (int r = 0; r < 4; ++r) {
        int row = wave * 32 + mt * 16 + quad * 4 + r;
        sm.xcb[row * 40 + xc_off + l16] = (__bf16)(acc3[mt][r] + bv);
      }
  }
  __syncthreads();
}

template <typename T>
__global__ __launch_bounds__(256) void cb_fused(
    const T* __restrict__ x,
    const T* __restrict__ pW1, const float* __restrict__ pb1,
    const T* __restrict__ pW2, const float* __restrict__ pb2,
    const T* __restrict__ pW3, const float* __restrict__ pb3,
    const T* __restrict__ nW1, const float* __restrict__ nb1,
    const T* __restrict__ nW2, const float* __restrict__ nb2,
    const T* __restrict__ nW3, const float* __restrict__ nb3,
    const T* __restrict__ cW1, const float* __restrict__ cb1,
    const T* __restrict__ cW2, const float* __restrict__ cb2,
    const T* __restrict__ cW3, const float* __restrict__ cb3,
    float* __restrict__ out_emb, float* __restrict__ out_con)
{
  __shared__ Smem sm;
  const int tid  = threadIdx.x;
  const int wave = tid >> 6, lane = tid & 63;
  const int quad = lane >> 4, l16 = lane & 15;
  const int row0 = blockIdx.x * BM_;
  const int c    = blockIdx.y;
  __bf16* wt2 = sm.ubuf;
  __bf16* hb  = sm.hbuf;

  run_bank(sm, x, pW1, pb1, pW2, pb2, pW3, pb3, c, row0, 0,  tid, wave, quad, l16);
  run_bank(sm, x, nW1, nb1, nW2, nb2, nW3, nb3, c, row0, 16, tid, wave, quad, l16);

  stage_wT72(cW1 + (size_t)c * (2 * E_ * H_), wt2, 2 * E_, tid);
  __syncthreads();
  f32x4 acc1[2][4]; zero_acc(acc1);
  {
    bf16x8 a[2], bb[4];
#pragma unroll
    for (int mt = 0; mt < 2; ++mt)
      a[mt] = *(const bf16x8*)&sm.xcb[(wave * 32 + mt * 16 + l16) * 40 + quad * 8];
#pragma unroll
    for (int nt = 0; nt < 4; ++nt)
      bb[nt] = *(const bf16x8*)&wt2[(nt * 16 + l16) * 72 + quad * 8];
#pragma unroll
    for (int mt = 0; mt < 2; ++mt)
#pragma unroll
      for (int nt = 0; nt < 4; ++nt)
        acc1[mt][nt] = mfma16(a[mt], bb[nt], acc1[mt][nt]);
  }
  __syncthreads();
  {
    const float* bias = cb1 + c * H_;
#pragma unroll
    for (int nt = 0; nt < 4; ++nt) {
      const int col = nt * 16 + l16;
      const float bv = bias[col];
#pragma unroll
      for (int mt = 0; mt < 2; ++mt)
#pragma unroll
        for (int r = 0; r < 4; ++r) {
          int row = wave * 32 + mt * 16 + quad * 4 + r;
          hb[row * 72 + col] = (__bf16)fmaxf(acc1[mt][nt][r] + bv, 0.f);
        }
    }
  }

  stage_wT72(cW2 + (size_t)c * (H_ * H_), wt2, 64, tid);
  __syncthreads();
  f32x4 acc2[2][4]; zero_acc(acc2);
  gemm64(hb, wt2, acc2, wave, quad, l16);
  __syncthreads();
  {
    const float* bias = cb2 + c * H_;
#pragma unroll
    for (int nt = 0; nt < 4; ++nt) {
      const int col = nt * 16 + l16;
      const float bv = bias[col];
#pragma unroll
      for (int mt = 0; mt < 2; ++mt)
#pragma unroll
        for (int r = 0; r < 4; ++r) {
          int row = wave * 32 + mt * 16 + quad * 4 + r;
          hb[row * 72 + col] = (__bf16)fmaxf(acc2[mt][nt][r] + bv, 0.f);
        }
    }
  }

  if (tid < 64) sm.w3s[tid] = (__bf16)(float)cW3[(size_t)c * H_ + tid];
  __syncthreads();
  if (tid < 128) {
    float s = cb3[c];
#pragma unroll
    for (int kc = 0; kc < 8; ++kc) {
      bf16x8 hv = *(const bf16x8*)&hb[tid * 72 + kc * 8];
      bf16x8 wv = *(const bf16x8*)&sm.w3s[kc * 8];
#pragma unroll
      for (int i = 0; i < 8; ++i) s += (float)hv[i] * (float)wv[i];
    }
    sm.conc[tid] = s;
  }
  __syncthreads();

  for (int ii = tid; ii < BM_ * E_; ii += 256) {
    int row = ii >> 4, e = ii & 15;
    float cv = sm.conc[row];
    float w  = fminf(fmaxf(cv * 0.5f + 0.5f, 0.f), 1.f);
    float pv = (float)sm.xcb[row * 40 + e];
    float nv = (float)sm.xcb[row * 40 + 16 + e];
    out_emb[(size_t)(row0 + row) * (E_ * C_) + e * C_ + c] = pv * w + nv * (1.f - w);
  }
  if (tid < 128) out_con[(size_t)(row0 + tid) * C_ + c] = sm.conc[tid];
}

// ============================== launch =======================================
extern "C" void kernel_launch(void* const* d_in, const int* in_sizes, int n_in,
                              void* d_out, int out_size, void* d_ws, size_t ws_size,
                              hipStream_t stream) {
  const float* xf   = (const float*)d_in[0];
  const float* pW1f = (const float*)d_in[1];
  const float* pb1f = (const float*)d_in[2];
  const float* pW2f = (const float*)d_in[3];
  const float* pb2f = (const float*)d_in[4];
  const float* pW3f = (const float*)d_in[5];
  const float* pb3f = (const float*)d_in[6];
  const float* nW1f = (const float*)d_in[7];
  const float* nb1f = (const float*)d_in[8];
  const float* nW2f = (const float*)d_in[9];
  const float* nb2f = (const float*)d_in[10];
  const float* nW3f = (const float*)d_in[11];
  const float* nb3f = (const float*)d_in[12];
  const float* cW1f = (const float*)d_in[13];
  const float* cb1f = (const float*)d_in[14];
  const float* cW2f = (const float*)d_in[15];
  const float* cb2f = (const float*)d_in[16];
  const float* cW3f = (const float*)d_in[17];
  const float* cb3f = (const float*)d_in[18];

  float* out_emb = (float*)d_out;
  float* out_con = out_emb + (size_t)B_ * E_ * C_;

  const int cx   = B_ * IN_;          // 6291456
  const int cW1c = C_ * IN_ * H_;     // 3145728
  const int cW2c = C_ * H_ * H_;      // 262144
  const int cW3c = C_ * H_ * E_;      // 65536
  const int ccW1 = C_ * 2 * E_ * H_;  // 131072
  const int ccW3 = C_ * H_;           // 4096
  const size_t total_el = (size_t)cx + 2 * cW1c + 3 * cW2c + 2 * cW3c + ccW1 + ccW3;
  const size_t need = total_el * 2;

  dim3 grid(B_ / BM_, C_);

  if (ws_size >= need) {
    __bf16* w = (__bf16*)d_ws;
    size_t o = 0;
    __bf16* xw   = w + o; o += cx;
    __bf16* pw1t = w + o; o += cW1c;
    __bf16* nw1t = w + o; o += cW1c;
    __bf16* pw2t = w + o; o += cW2c;
    __bf16* nw2t = w + o; o += cW2c;
    __bf16* cw2t = w + o; o += cW2c;
    __bf16* pw3t = w + o; o += cW3c;
    __bf16* nw3t = w + o; o += cW3c;
    __bf16* cw1t = w + o; o += ccW1;
    __bf16* cw3w = w + o; o += ccW3;

    PrepArgs a;
    const float* srcs[PSEG] = {xf,  cW3f, pW1f, nW1f, pW2f, nW2f, cW2f, cW1f, pW3f, nW3f};
    __bf16*      dsts[PSEG] = {xw,  cw3w, pw1t, nw1t, pw2t, nw2t, cw2t, cw1t, pw3t, nw3t};
    const int    Ks[PSEG]   = {0,   0,    768,  768,  64,   64,   64,   32,   64,   64};
    const int    Ns[PSEG]   = {1,   1,    64,   64,   64,   64,   64,   64,   16,   16};
    const int    els[PSEG]  = {cx,  ccW3, cW1c, cW1c, cW2c, cW2c, cW2c, ccW1, cW3c, cW3c};
    int b = 0;
    for (int i = 0; i < PSEG; ++i) {
      a.src[i] = srcs[i]; a.dst[i] = dsts[i];
      a.kdiv8[i] = (Ns[i] == 1) ? (els[i] / 8) : (Ks[i] / 8);
      a.N[i] = Ns[i];
      a.bstart[i] = b;
      b += (els[i] / 8 + 255) / 256;
    }
    a.bstart[PSEG] = b;
    prep<<<b, 256, 0, stream>>>(a);

    cb_fused_t<<<grid, 256, 0, stream>>>(xw,
        pw1t, pb1f, pw2t, pb2f, pw3t, pb3f,
        nw1t, nb1f, nw2t, nb2f, nw3t, nb3f,
        cw1t, cb1f, cw2t, cb2f, cw3w, cb3f,
        out_emb, out_con);
  } else {
    cb_fused<float><<<grid, 256, 0, stream>>>(xf,
        pW1f, pb1f, pW2f, pb2f, pW3f, pb3f,
        nW1f, nb1f, nW2f, nb2f, nW3f, nb3f,
        cW1f, cb1f, cW2f, cb2f, cW3f, cb3f,
        out_emb, out_con);
  }
}